// Round 2
// baseline (10296.696 us; speedup 1.0000x reference)
//
#include <hip/hip_runtime.h>
#include <hip/hip_bf16.h>
#include <math.h>

static constexpr int HWPX = 16384;  // 128*128
static constexpr int IMGW = 128;

__device__ inline float sigmoidf_(float x) { return 1.0f / (1.0f + expf(-x)); }

// ---------------- conv 3x3 SAME + bias + ReLU, 4 couts/block, fp32 out -------
__global__ __launch_bounds__(256) void conv3x3_relu4(
    const float* __restrict__ in, const float* __restrict__ w,
    const float* __restrict__ bias, float* __restrict__ out, int Cin)
{
    const int Cout = gridDim.y * 4;
    const int cout0 = blockIdx.y * 4;
    const int img = blockIdx.z;
    __shared__ float lw[4 * 128 * 9];
    const int nW = 4 * Cin * 9;
    const float* wbase = w + (size_t)cout0 * Cin * 9;
    for (int i = threadIdx.x; i < nW; i += 256) lw[i] = wbase[i];
    __syncthreads();

    const int x = threadIdx.x & 127;
    const int y0 = blockIdx.x * 8 + (threadIdx.x >> 7) * 4;  // 4 rows per thread
    const float* inImg = in + (size_t)img * Cin * HWPX;

    const int cxm = x > 0 ? x - 1 : 0;
    const int cxp = x < 127 ? x + 1 : 127;
    const bool xok0 = x > 0, xok2 = x < 127;

    float acc[4][4];
#pragma unroll
    for (int co = 0; co < 4; ++co)
#pragma unroll
        for (int r = 0; r < 4; ++r) acc[co][r] = 0.f;

    for (int ci = 0; ci < Cin; ++ci) {
        const float* p = inImg + (size_t)ci * HWPX;
        float v[6][3];
#pragma unroll
        for (int r = 0; r < 6; ++r) {
            int y = y0 - 1 + r;
            bool yok = (y >= 0) && (y < 128);
            int cy = y < 0 ? 0 : (y > 127 ? 127 : y);
            const float* row = p + cy * IMGW;
            float v0 = row[cxm];
            float v1 = row[x];
            float v2 = row[cxp];
            v[r][0] = (yok && xok0) ? v0 : 0.f;
            v[r][1] = yok ? v1 : 0.f;
            v[r][2] = (yok && xok2) ? v2 : 0.f;
        }
        const float* lwc = &lw[ci * 9];
#pragma unroll
        for (int co = 0; co < 4; ++co) {
            const float* wr = lwc + co * Cin * 9;
#pragma unroll
            for (int r = 0; r < 4; ++r) {
                acc[co][r] += wr[0] * v[r][0] + wr[1] * v[r][1] + wr[2] * v[r][2]
                            + wr[3] * v[r + 1][0] + wr[4] * v[r + 1][1] + wr[5] * v[r + 1][2]
                            + wr[6] * v[r + 2][0] + wr[7] * v[r + 2][1] + wr[8] * v[r + 2][2];
            }
        }
    }
#pragma unroll
    for (int co = 0; co < 4; ++co) {
        float bb = bias[cout0 + co];
        float* op = out + ((size_t)img * Cout + cout0 + co) * HWPX;
#pragma unroll
        for (int r = 0; r < 4; ++r) {
            float vv = acc[co][r] + bb;
            op[(y0 + r) * IMGW + x] = vv > 0.f ? vv : 0.f;
        }
    }
}

// ---------------- spatial softmax -> (ex, ey) per (img, channel) -------------
__global__ __launch_bounds__(256) void spatial_softmax_k(
    const float* __restrict__ act,   // (chunk, 16, 128, 128) fp32
    float* __restrict__ feat,        // (40, 32) fp32, interleaved ex,ey
    int imgBase)
{
    const int ch = blockIdx.x & 15;
    const int li = blockIdx.x >> 4;
    const float* p = act + ((size_t)li * 16 + ch) * HWPX;
    __shared__ float r0[256], r1[256], r2[256];
    const int tid = threadIdx.x;

    float m = -1e30f;
    for (int i = tid; i < HWPX; i += 256) m = fmaxf(m, p[i]);
    r0[tid] = m;
    __syncthreads();
    for (int s = 128; s > 0; s >>= 1) {
        if (tid < s) r0[tid] = fmaxf(r0[tid], r0[tid + s]);
        __syncthreads();
    }
    m = r0[0];
    __syncthreads();

    float s = 0.f, sx = 0.f, sy = 0.f;
    for (int i = tid; i < HWPX; i += 256) {
        float e = expf(p[i] - m);
        int xx = i & 127, yy = i >> 7;
        s += e;
        sx += e * (-1.f + (2.f / 127.f) * xx);
        sy += e * (-1.f + (2.f / 127.f) * yy);
    }
    r0[tid] = s; r1[tid] = sx; r2[tid] = sy;
    __syncthreads();
    for (int st = 128; st > 0; st >>= 1) {
        if (tid < st) {
            r0[tid] += r0[tid + st];
            r1[tid] += r1[tid + st];
            r2[tid] += r2[tid + st];
        }
        __syncthreads();
    }
    if (tid == 0) {
        float inv = 1.f / r0[0];
        feat[(size_t)(imgBase + li) * 32 + 2 * ch] = r1[0] * inv;      // ex (POSX)
        feat[(size_t)(imgBase + li) * 32 + 2 * ch + 1] = r2[0] * inv;  // ey (POSY)
    }
}

// ---------------- LSTM ------------------------------------------------------
__device__ inline float imgfeat(const float* featm, const float* feats,
                                int b, int t, int k)
{
    int idx = (b * 10 + t) * 32;
    return k < 32 ? featm[idx + k] : feats[idx + k - 32];
}

// gate pre-activations: gates[b][r] = bih[r]+bhh[r] + wih[r]·x_b + whh[r]·h_b
__global__ __launch_bounds__(256) void lstm_gates_k(
    const float* __restrict__ wih, const float* __restrict__ whh,
    const float* __restrict__ bih, const float* __restrict__ bhh,
    const float* __restrict__ states,
    const float* __restrict__ featm, const float* __restrict__ feats,
    const float* __restrict__ hprev,  // h[l-1] (B,512) or nullptr (layer 0)
    const float* __restrict__ hl,     // h[l]   (B,512) from t-1
    float* __restrict__ gates,        // (B, 2048)
    int t, int inLen)
{
    const int b = blockIdx.x >> 3;                       // 8 blocks per batch elem
    const int r = ((blockIdx.x & 7) << 8) + threadIdx.x; // gate row 0..2047
    __shared__ float xs[576];
    __shared__ float hs[512];
    for (int i = threadIdx.x; i < inLen; i += 256) {
        float v;
        if (hprev) {
            v = (i < 512) ? hprev[b * 512 + i] : imgfeat(featm, feats, b, t, i - 512);
        } else {
            v = (i < 6) ? states[(b * 10 + t) * 6 + i]
                        : imgfeat(featm, feats, b, t, i - 6);
        }
        xs[i] = v;
    }
    for (int i = threadIdx.x; i < 512; i += 256) hs[i] = hl[b * 512 + i];
    __syncthreads();

    float acc = bih[r] + bhh[r];
    const float* wr = wih + (size_t)r * inLen;
    if ((inLen & 3) == 0) {  // rows 16B-aligned (576 case)
        const float4* wv = reinterpret_cast<const float4*>(wr);
        const int n4 = inLen >> 2;
        for (int k4 = 0; k4 < n4; ++k4) {
            float4 u = wv[k4];
            const float* xp = &xs[k4 << 2];
            acc += u.x * xp[0] + u.y * xp[1] + u.z * xp[2] + u.w * xp[3];
        }
    } else {
        for (int k = 0; k < inLen; ++k) acc += wr[k] * xs[k];
    }
    {
        const float4* wv = reinterpret_cast<const float4*>(whh + (size_t)r * 512);
        for (int k4 = 0; k4 < 128; ++k4) {
            float4 u = wv[k4];
            const float* xp = &hs[k4 << 2];
            acc += u.x * xp[0] + u.y * xp[1] + u.z * xp[2] + u.w * xp[3];
        }
    }
    gates[b * 2048 + r] = acc;
}

// torch LSTMCell gate order i,f,g,o
__global__ __launch_bounds__(256) void lstm_combine_k(
    const float* __restrict__ gates, float* __restrict__ h, float* __restrict__ c)
{
    int gid = blockIdx.x * 256 + threadIdx.x;  // 0..2047
    if (gid >= 2048) return;
    int b = gid >> 9, j = gid & 511;
    float gi = gates[b * 2048 + j];
    float gf = gates[b * 2048 + 512 + j];
    float gg = gates[b * 2048 + 1024 + j];
    float go = gates[b * 2048 + 1536 + j];
    float cp = c[b * 512 + j];
    float c2 = sigmoidf_(gf) * cp + sigmoidf_(gi) * tanhf(gg);
    float h2 = sigmoidf_(go) * tanhf(c2);
    c[b * 512 + j] = c2;
    h[b * 512 + j] = h2;
}

__global__ __launch_bounds__(64) void out_proj_k(
    const float* __restrict__ h5, const float* __restrict__ featm,
    const float* __restrict__ feats, const float* __restrict__ out_w,
    const float* __restrict__ out_b, float* __restrict__ out, int t)
{
    int tid = threadIdx.x;
    if (tid >= 24) return;
    int b = tid / 6, a = tid % 6;
    const float* wr = out_w + a * 576;
    float acc = out_b[a];
    for (int k = 0; k < 512; ++k) acc += wr[k] * h5[b * 512 + k];
    for (int k = 0; k < 64; ++k) acc += wr[512 + k] * imgfeat(featm, feats, b, t, k);
    out[(b * 10 + t) * 6 + a] = acc;
}

// ---------------- host orchestration ----------------------------------------
extern "C" void kernel_launch(void* const* d_in, const int* in_sizes, int n_in,
                              void* d_out, int out_size, void* d_ws, size_t ws_size,
                              hipStream_t stream)
{
    const float* seq_m = (const float*)d_in[0];
    const float* seq_s = (const float*)d_in[1];
    const float* states = (const float*)d_in[2];
    const float *cw[2][4], *cb[2][4];
    for (int cam = 0; cam < 2; ++cam)
        for (int j = 0; j < 4; ++j) {
            cw[cam][j] = (const float*)d_in[3 + cam * 8 + j * 2];
            cb[cam][j] = (const float*)d_in[3 + cam * 8 + j * 2 + 1];
        }
    const float* wih0  = (const float*)d_in[19];
    const float* whh0  = (const float*)d_in[20];
    const float* bih0  = (const float*)d_in[21];
    const float* bhh0  = (const float*)d_in[22];
    const float* wih_r = (const float*)d_in[23];
    const float* whh_r = (const float*)d_in[24];
    const float* bih_r = (const float*)d_in[25];
    const float* bhh_r = (const float*)d_in[26];
    const float* out_w = (const float*)d_in[27];
    const float* out_b = (const float*)d_in[28];
    float* out = (float*)d_out;

    char* ws = (char*)d_ws;
    float* featm = (float*)ws; ws += 40 * 32 * 4;
    float* feats = (float*)ws; ws += 40 * 32 * 4;
    float* hbuf  = (float*)ws; ws += 6 * 4 * 512 * 4;
    float* cbuf  = (float*)ws; ws += 6 * 4 * 512 * 4;
    float* gates = (float*)ws; ws += 4 * 2048 * 4;
    size_t used = (size_t)(ws - (char*)d_ws);
    size_t rem = ws_size > used ? ws_size - used : 0;
    // chunk of images per conv pass; ping-pong buffers need CH*192*HWPX floats
    int CH = 1;
    const int cands[8] = {40, 20, 10, 8, 5, 4, 2, 1};
    for (int i = 0; i < 8; ++i) {
        size_t need = (size_t)cands[i] * 192 * HWPX * 4;
        if (need <= rem) { CH = cands[i]; break; }
    }
    float* buf0 = (float*)ws;                       // CH*128*HWPX fp32
    float* buf1 = buf0 + (size_t)CH * 128 * HWPX;   // CH*64*HWPX fp32

    // h,c zero-init each call (ws is re-poisoned by the harness)
    hipMemsetAsync(hbuf, 0, 2 * 6 * 4 * 512 * 4, stream);

    // ---- CNN + spatial softmax, both cameras, chunked ----
    for (int cam = 0; cam < 2; ++cam) {
        const float* src = cam ? seq_s : seq_m;
        float* feat = cam ? feats : featm;
        for (int c0 = 0; c0 < 40; c0 += CH) {
            conv3x3_relu4<<<dim3(16, 8, CH), 256, 0, stream>>>(
                src + (size_t)c0 * 3 * HWPX, cw[cam][0], cb[cam][0], buf0, 3);
            conv3x3_relu4<<<dim3(16, 16, CH), 256, 0, stream>>>(
                buf0, cw[cam][1], cb[cam][1], buf1, 32);
            conv3x3_relu4<<<dim3(16, 32, CH), 256, 0, stream>>>(
                buf1, cw[cam][2], cb[cam][2], buf0, 64);
            conv3x3_relu4<<<dim3(16, 4, CH), 256, 0, stream>>>(
                buf0, cw[cam][3], cb[cam][3], buf1, 128);
            spatial_softmax_k<<<CH * 16, 256, 0, stream>>>(buf1, feat, c0);
        }
    }

    // ---- LSTM over time, 6 layers, + output projection ----
    for (int t = 0; t < 10; ++t) {
        lstm_gates_k<<<32, 256, 0, stream>>>(wih0, whh0, bih0, bhh0, states,
                                             featm, feats, nullptr, hbuf, gates,
                                             t, 70);
        lstm_combine_k<<<8, 256, 0, stream>>>(gates, hbuf, cbuf);
        for (int l = 1; l < 6; ++l) {
            lstm_gates_k<<<32, 256, 0, stream>>>(
                wih_r + (size_t)(l - 1) * 2048 * 576,
                whh_r + (size_t)(l - 1) * 2048 * 512,
                bih_r + (size_t)(l - 1) * 2048,
                bhh_r + (size_t)(l - 1) * 2048,
                states, featm, feats,
                hbuf + (size_t)(l - 1) * 2048, hbuf + (size_t)l * 2048,
                gates, t, 576);
            lstm_combine_k<<<8, 256, 0, stream>>>(gates, hbuf + (size_t)l * 2048,
                                                  cbuf + (size_t)l * 2048);
        }
        out_proj_k<<<1, 64, 0, stream>>>(hbuf + 5 * 2048, featm, feats,
                                         out_w, out_b, out, t);
    }
}

// Round 3
// 3734.733 us; speedup vs baseline: 2.7570x; 2.7570x over previous
//
#include <hip/hip_runtime.h>
#include <hip/hip_bf16.h>
#include <math.h>

typedef __hip_bfloat16 bf16;
typedef short bf16x8 __attribute__((ext_vector_type(8)));
typedef float f32x4 __attribute__((ext_vector_type(4)));

static constexpr int HWPX = 16384;  // 128*128
static constexpr int IMGW = 128;

__device__ inline float sigmoidf_(float x) { return 1.0f / (1.0f + expf(-x)); }

// ---------------- prep: fp32 -> bf16 convert -------------------------------
__global__ __launch_bounds__(256) void tobf16_k(const float* __restrict__ src,
                                                bf16* __restrict__ dst, int n)
{
    for (int i = blockIdx.x * 256 + threadIdx.x; i < n; i += gridDim.x * 256)
        dst[i] = __float2bfloat16(src[i]);
}

// ---------------- prep: weight transpose to [tap][co][ci_pad] bf16 ----------
__global__ __launch_bounds__(256) void wprep_k(const float* __restrict__ w,
                                               bf16* __restrict__ wT,
                                               int CIN, int CINP, int COUT)
{
    int total = 9 * COUT * CINP;
    for (int i = blockIdx.x * 256 + threadIdx.x; i < total; i += gridDim.x * 256) {
        int ci = i % CINP;
        int t2 = i / CINP;
        int co = t2 % COUT;
        int tap = t2 / COUT;
        float v = (ci < CIN) ? w[(co * CIN + ci) * 9 + tap] : 0.f;
        wT[i] = __float2bfloat16(v);
    }
}

// ---------------- MFMA conv 3x3 SAME + bias + ReLU --------------------------
// Block: one image row (128 px) x full COUT. 4 waves, wave grid WM x WN.
// LDS: input tile [3 rows][130 x][32 ci] bf16, x-stride 40 shorts (16B-aligned
// b128 frags, odd-dword bank spread). K order: (tap, ci-chunk-of-32).
template <int CIN, int COUT, int WM, int WN>
__global__ __launch_bounds__(256) void conv_mfma(
    const bf16* __restrict__ in,   // [img][CIN][128][128], img chunk-local
    const bf16* __restrict__ wT,   // [9][COUT][CINP]
    const float* __restrict__ bias,
    bf16* __restrict__ out)        // [img][COUT][128][128]
{
    constexpr int KC = (CIN + 31) / 32;
    constexpr int CINP = KC * 32;
    constexpr int MW = COUT / 16 / WM;  // m-tiles per wave
    constexpr int NW = 8 / WN;          // n-tiles per wave
    constexpr int XS = 40;              // shorts per x slot (32 data + 8 pad)

    const int y = blockIdx.x;
    const int img = blockIdx.z;
    const int tid = threadIdx.x;
    const int wave = tid >> 6, lane = tid & 63;
    const int wm = wave % WM, wn = wave / WM;
    const int q = lane >> 4, n16 = lane & 15;

    __shared__ short smem[3 * 130 * XS];
    const unsigned short* inu = reinterpret_cast<const unsigned short*>(in);

    f32x4 acc[MW][NW];
#pragma unroll
    for (int mt = 0; mt < MW; ++mt)
#pragma unroll
        for (int nt = 0; nt < NW; ++nt) acc[mt][nt] = f32x4{0.f, 0.f, 0.f, 0.f};

    const size_t imgBase = (size_t)img * CIN * HWPX;

    for (int kc = 0; kc < KC; ++kc) {
        if (kc) __syncthreads();
        // stage 3 rows x 130 x-positions x 32 ci (2 ci packed per dword)
        for (int d = tid; d < 3 * 16 * 130; d += 256) {
            int x = d % 130;
            int t = d / 130;
            int cp = t % 16, r = t / 16;
            int ci = kc * 32 + 2 * cp;
            int yy = y + r - 1, xx = x - 1;
            unsigned val = 0;
            if ((unsigned)yy < 128u && (unsigned)xx < 128u) {
                const unsigned short* p = inu + imgBase + yy * IMGW + xx;
                unsigned lo = (ci < CIN) ? (unsigned)p[(size_t)ci * HWPX] : 0u;
                unsigned hi = (ci + 1 < CIN) ? (unsigned)p[(size_t)(ci + 1) * HWPX] : 0u;
                val = lo | (hi << 16);
            }
            reinterpret_cast<unsigned*>(smem)[(r * 130 + x) * (XS / 2) + cp] = val;
        }
        __syncthreads();

#pragma unroll
        for (int tap = 0; tap < 9; ++tap) {
            const int ky = tap / 3, kx = tap % 3;
            bf16x8 aF[MW];
#pragma unroll
            for (int mt = 0; mt < MW; ++mt) {
                int co = (wm * MW + mt) * 16 + n16;
                const bf16* ap = wT + ((size_t)tap * COUT + co) * CINP + kc * 32 + q * 8;
                aF[mt] = *(const bf16x8*)(const void*)ap;
            }
#pragma unroll
            for (int nt = 0; nt < NW; ++nt) {
                int x = (wn * NW + nt) * 16 + n16;  // pixel x
                const short* bp = &smem[(ky * 130 + x + kx) * XS + q * 8];
                bf16x8 bF = *(const bf16x8*)(const void*)bp;
#pragma unroll
                for (int mt = 0; mt < MW; ++mt)
                    acc[mt][nt] = __builtin_amdgcn_mfma_f32_16x16x32_bf16(
                        aF[mt], bF, acc[mt][nt], 0, 0, 0);
            }
        }
    }

    // epilogue: C layout col=lane&15 (pixel), row=quad*4+reg (cout)
#pragma unroll
    for (int mt = 0; mt < MW; ++mt) {
        int co_b = (wm * MW + mt) * 16 + q * 4;
#pragma unroll
        for (int nt = 0; nt < NW; ++nt) {
            int x = (wn * NW + nt) * 16 + n16;
#pragma unroll
            for (int r = 0; r < 4; ++r) {
                int co = co_b + r;
                float v = acc[mt][nt][r] + bias[co];
                v = v > 0.f ? v : 0.f;
                out[((size_t)img * COUT + co) * HWPX + y * IMGW + x] = __float2bfloat16(v);
            }
        }
    }
}

// ---------------- spatial softmax (bf16 act) -> (ex, ey) --------------------
__global__ __launch_bounds__(256) void spatial_softmax_k(
    const bf16* __restrict__ act,   // (chunk, 16, 128, 128) bf16
    float* __restrict__ feat,       // (40, 32) fp32, interleaved ex,ey
    int imgBase)
{
    const int ch = blockIdx.x & 15;
    const int li = blockIdx.x >> 4;
    const bf16* p = act + ((size_t)li * 16 + ch) * HWPX;
    __shared__ float r0[256], r1[256], r2[256];
    const int tid = threadIdx.x;

    float m = -1e30f;
    for (int i = tid; i < HWPX; i += 256) m = fmaxf(m, __bfloat162float(p[i]));
    r0[tid] = m;
    __syncthreads();
    for (int s = 128; s > 0; s >>= 1) {
        if (tid < s) r0[tid] = fmaxf(r0[tid], r0[tid + s]);
        __syncthreads();
    }
    m = r0[0];
    __syncthreads();

    float s = 0.f, sx = 0.f, sy = 0.f;
    for (int i = tid; i < HWPX; i += 256) {
        float e = expf(__bfloat162float(p[i]) - m);
        int xx = i & 127, yy = i >> 7;
        s += e;
        sx += e * (-1.f + (2.f / 127.f) * xx);
        sy += e * (-1.f + (2.f / 127.f) * yy);
    }
    r0[tid] = s; r1[tid] = sx; r2[tid] = sy;
    __syncthreads();
    for (int st = 128; st > 0; st >>= 1) {
        if (tid < st) {
            r0[tid] += r0[tid + st];
            r1[tid] += r1[tid + st];
            r2[tid] += r2[tid + st];
        }
        __syncthreads();
    }
    if (tid == 0) {
        float inv = 1.f / r0[0];
        feat[(size_t)(imgBase + li) * 32 + 2 * ch] = r1[0] * inv;      // ex
        feat[(size_t)(imgBase + li) * 32 + 2 * ch + 1] = r2[0] * inv;  // ey
    }
}

// ---------------- LSTM (fp32, unchanged from R2) ----------------------------
__device__ inline float imgfeat(const float* featm, const float* feats,
                                int b, int t, int k)
{
    int idx = (b * 10 + t) * 32;
    return k < 32 ? featm[idx + k] : feats[idx + k - 32];
}

__global__ __launch_bounds__(256) void lstm_gates_k(
    const float* __restrict__ wih, const float* __restrict__ whh,
    const float* __restrict__ bih, const float* __restrict__ bhh,
    const float* __restrict__ states,
    const float* __restrict__ featm, const float* __restrict__ feats,
    const float* __restrict__ hprev, const float* __restrict__ hl,
    float* __restrict__ gates, int t, int inLen)
{
    const int b = blockIdx.x >> 3;
    const int r = ((blockIdx.x & 7) << 8) + threadIdx.x;
    __shared__ float xs[576];
    __shared__ float hs[512];
    for (int i = threadIdx.x; i < inLen; i += 256) {
        float v;
        if (hprev) {
            v = (i < 512) ? hprev[b * 512 + i] : imgfeat(featm, feats, b, t, i - 512);
        } else {
            v = (i < 6) ? states[(b * 10 + t) * 6 + i]
                        : imgfeat(featm, feats, b, t, i - 6);
        }
        xs[i] = v;
    }
    for (int i = threadIdx.x; i < 512; i += 256) hs[i] = hl[b * 512 + i];
    __syncthreads();

    float acc = bih[r] + bhh[r];
    const float* wr = wih + (size_t)r * inLen;
    if ((inLen & 3) == 0) {
        const float4* wv = reinterpret_cast<const float4*>(wr);
        const int n4 = inLen >> 2;
        for (int k4 = 0; k4 < n4; ++k4) {
            float4 u = wv[k4];
            const float* xp = &xs[k4 << 2];
            acc += u.x * xp[0] + u.y * xp[1] + u.z * xp[2] + u.w * xp[3];
        }
    } else {
        for (int k = 0; k < inLen; ++k) acc += wr[k] * xs[k];
    }
    {
        const float4* wv = reinterpret_cast<const float4*>(whh + (size_t)r * 512);
        for (int k4 = 0; k4 < 128; ++k4) {
            float4 u = wv[k4];
            const float* xp = &hs[k4 << 2];
            acc += u.x * xp[0] + u.y * xp[1] + u.z * xp[2] + u.w * xp[3];
        }
    }
    gates[b * 2048 + r] = acc;
}

__global__ __launch_bounds__(256) void lstm_combine_k(
    const float* __restrict__ gates, float* __restrict__ h, float* __restrict__ c)
{
    int gid = blockIdx.x * 256 + threadIdx.x;
    if (gid >= 2048) return;
    int b = gid >> 9, j = gid & 511;
    float gi = gates[b * 2048 + j];
    float gf = gates[b * 2048 + 512 + j];
    float gg = gates[b * 2048 + 1024 + j];
    float go = gates[b * 2048 + 1536 + j];
    float cp = c[b * 512 + j];
    float c2 = sigmoidf_(gf) * cp + sigmoidf_(gi) * tanhf(gg);
    float h2 = sigmoidf_(go) * tanhf(c2);
    c[b * 512 + j] = c2;
    h[b * 512 + j] = h2;
}

__global__ __launch_bounds__(64) void out_proj_k(
    const float* __restrict__ h5, const float* __restrict__ featm,
    const float* __restrict__ feats, const float* __restrict__ out_w,
    const float* __restrict__ out_b, float* __restrict__ out, int t)
{
    int tid = threadIdx.x;
    if (tid >= 24) return;
    int b = tid / 6, a = tid % 6;
    const float* wr = out_w + a * 576;
    float acc = out_b[a];
    for (int k = 0; k < 512; ++k) acc += wr[k] * h5[b * 512 + k];
    for (int k = 0; k < 64; ++k) acc += wr[512 + k] * imgfeat(featm, feats, b, t, k);
    out[(b * 10 + t) * 6 + a] = acc;
}

// ---------------- host orchestration ----------------------------------------
extern "C" void kernel_launch(void* const* d_in, const int* in_sizes, int n_in,
                              void* d_out, int out_size, void* d_ws, size_t ws_size,
                              hipStream_t stream)
{
    const float* seq_m = (const float*)d_in[0];
    const float* seq_s = (const float*)d_in[1];
    const float* states = (const float*)d_in[2];
    const float *cw[2][4], *cb[2][4];
    for (int cam = 0; cam < 2; ++cam)
        for (int j = 0; j < 4; ++j) {
            cw[cam][j] = (const float*)d_in[3 + cam * 8 + j * 2];
            cb[cam][j] = (const float*)d_in[3 + cam * 8 + j * 2 + 1];
        }
    const float* wih0  = (const float*)d_in[19];
    const float* whh0  = (const float*)d_in[20];
    const float* bih0  = (const float*)d_in[21];
    const float* bhh0  = (const float*)d_in[22];
    const float* wih_r = (const float*)d_in[23];
    const float* whh_r = (const float*)d_in[24];
    const float* bih_r = (const float*)d_in[25];
    const float* bhh_r = (const float*)d_in[26];
    const float* out_w = (const float*)d_in[27];
    const float* out_b = (const float*)d_in[28];
    float* out = (float*)d_out;

    // ---- workspace layout ----
    char* ws = (char*)d_ws;
    float* featm = (float*)ws; ws += 40 * 32 * 4;
    float* feats = (float*)ws; ws += 40 * 32 * 4;
    float* hbuf  = (float*)ws; ws += 6 * 4 * 512 * 4;
    float* cbuf  = (float*)ws; ws += 6 * 4 * 512 * 4;
    float* gates = (float*)ws; ws += 4 * 2048 * 4;
    // transposed bf16 weights per cam/layer: [9][COUT][CINP]
    const int wtElts[4] = {9 * 32 * 32, 9 * 64 * 32, 9 * 128 * 64, 9 * 16 * 128};
    const int CINs[4] = {3, 32, 64, 128};
    const int CINPs[4] = {32, 32, 64, 128};
    const int COUTs[4] = {32, 64, 128, 16};
    bf16* wT[2][4];
    for (int cam = 0; cam < 2; ++cam)
        for (int j = 0; j < 4; ++j) {
            wT[cam][j] = (bf16*)ws; ws += wtElts[j] * 2;
        }
    bf16* inb[2];
    inb[0] = (bf16*)ws; ws += (size_t)40 * 3 * HWPX * 2;
    inb[1] = (bf16*)ws; ws += (size_t)40 * 3 * HWPX * 2;

    size_t used = (size_t)(ws - (char*)d_ws);
    size_t rem = ws_size > used ? ws_size - used : 0;
    int CH = 1;
    const int cands[8] = {40, 20, 10, 8, 5, 4, 2, 1};
    for (int i = 0; i < 8; ++i) {
        size_t need = (size_t)cands[i] * (128 + 64) * HWPX * 2;
        if (need <= rem) { CH = cands[i]; break; }
    }
    bf16* bufA = (bf16*)ws;                        // CH*128ch
    bf16* bufB = bufA + (size_t)CH * 128 * HWPX;   // CH*64ch

    hipMemsetAsync(hbuf, 0, 2 * 6 * 4 * 512 * 4, stream);

    // ---- prep: convert inputs + transpose weights to bf16 ----
    tobf16_k<<<512, 256, 0, stream>>>(seq_m, inb[0], 40 * 3 * HWPX);
    tobf16_k<<<512, 256, 0, stream>>>(seq_s, inb[1], 40 * 3 * HWPX);
    for (int cam = 0; cam < 2; ++cam)
        for (int j = 0; j < 4; ++j)
            wprep_k<<<(wtElts[j] + 255) / 256, 256, 0, stream>>>(
                cw[cam][j], wT[cam][j], CINs[j], CINPs[j], COUTs[j]);

    // ---- CNN + spatial softmax ----
    for (int cam = 0; cam < 2; ++cam) {
        float* feat = cam ? feats : featm;
        for (int c0 = 0; c0 < 40; c0 += CH) {
            int ch = (40 - c0) < CH ? (40 - c0) : CH;
            conv_mfma<3, 32, 2, 2><<<dim3(128, 1, ch), 256, 0, stream>>>(
                inb[cam] + (size_t)c0 * 3 * HWPX, wT[cam][0], cb[cam][0], bufA);
            conv_mfma<32, 64, 2, 2><<<dim3(128, 1, ch), 256, 0, stream>>>(
                bufA, wT[cam][1], cb[cam][1], bufB);
            conv_mfma<64, 128, 2, 2><<<dim3(128, 1, ch), 256, 0, stream>>>(
                bufB, wT[cam][2], cb[cam][2], bufA);
            conv_mfma<128, 16, 1, 4><<<dim3(128, 1, ch), 256, 0, stream>>>(
                bufA, wT[cam][3], cb[cam][3], bufB);
            spatial_softmax_k<<<ch * 16, 256, 0, stream>>>(bufB, feat, c0);
        }
    }

    // ---- LSTM over time ----
    for (int t = 0; t < 10; ++t) {
        lstm_gates_k<<<32, 256, 0, stream>>>(wih0, whh0, bih0, bhh0, states,
                                             featm, feats, nullptr, hbuf, gates,
                                             t, 70);
        lstm_combine_k<<<8, 256, 0, stream>>>(gates, hbuf, cbuf);
        for (int l = 1; l < 6; ++l) {
            lstm_gates_k<<<32, 256, 0, stream>>>(
                wih_r + (size_t)(l - 1) * 2048 * 576,
                whh_r + (size_t)(l - 1) * 2048 * 512,
                bih_r + (size_t)(l - 1) * 2048,
                bhh_r + (size_t)(l - 1) * 2048,
                states, featm, feats,
                hbuf + (size_t)(l - 1) * 2048, hbuf + (size_t)l * 2048,
                gates, t, 576);
            lstm_combine_k<<<8, 256, 0, stream>>>(gates, hbuf + (size_t)l * 2048,
                                                  cbuf + (size_t)l * 2048);
        }
        out_proj_k<<<1, 64, 0, stream>>>(hbuf + 5 * 2048, featm, feats,
                                         out_w, out_b, out, t);
    }
}

// Round 4
// 2253.237 us; speedup vs baseline: 4.5697x; 1.6575x over previous
//
#include <hip/hip_runtime.h>
#include <hip/hip_bf16.h>
#include <math.h>

typedef __hip_bfloat16 bf16;
typedef short bf16x8 __attribute__((ext_vector_type(8)));
typedef float f32x4 __attribute__((ext_vector_type(4)));

static constexpr int HWPX = 16384;  // 128*128

__device__ inline float sigmoidf_(float x) { return 1.0f / (1.0f + expf(-x)); }
__device__ inline float bflo(unsigned u) { return __uint_as_float(u << 16); }
__device__ inline float bfhi(unsigned u) { return __uint_as_float(u & 0xffff0000u); }

// ---------------- prep: fp32 NCHW image -> bf16 NHWC8 -----------------------
__global__ __launch_bounds__(256) void prep8_k(const float* __restrict__ src,
                                               bf16* __restrict__ dst, int npx)
{
    int p = blockIdx.x * 256 + threadIdx.x;
    if (p >= npx) return;
    int img = p >> 14, rem = p & 16383;
    const float* s = src + (size_t)img * 3 * HWPX + rem;
    bf16* d = dst + (size_t)p * 8;
    d[0] = __float2bfloat16(s[0]);
    d[1] = __float2bfloat16(s[HWPX]);
    d[2] = __float2bfloat16(s[2 * HWPX]);
    bf16 z = __float2bfloat16(0.f);
    d[3] = z; d[4] = z; d[5] = z; d[6] = z; d[7] = z;
}

// ---------------- prep: conv weights [co][ci][3][3] -> [tap][co][ci] bf16 ---
__global__ __launch_bounds__(256) void wprep_k(const float* __restrict__ w,
                                               bf16* __restrict__ wT,
                                               int CIN, int COUT)
{
    int total = 9 * COUT * CIN;
    for (int i = blockIdx.x * 256 + threadIdx.x; i < total; i += gridDim.x * 256) {
        int ci = i % CIN;
        int t = i / CIN;
        int co = t % COUT;
        int tap = t / COUT;
        wT[i] = __float2bfloat16(w[(co * CIN + ci) * 9 + tap]);
    }
}

// L0: [3ky][32co][32k] where k = kx*8 + c (c<3 real, kx<3 real, rest 0)
__global__ __launch_bounds__(256) void wprep0_k(const float* __restrict__ w,
                                                bf16* __restrict__ wT0)
{
    int i = blockIdx.x * 256 + threadIdx.x;  // 3*32*32 = 3072
    if (i >= 3072) return;
    int k = i & 31, co = (i >> 5) & 31, ky = i >> 10;
    int kx = k >> 3, c = k & 7;
    float v = (kx < 3 && c < 3) ? w[((co * 3 + c) * 3 + ky) * 3 + kx] : 0.f;
    wT0[i] = __float2bfloat16(v);
}

// ---------------- prep: fp32 matrix -> bf16 with column pad -----------------
__global__ __launch_bounds__(256) void padcvt_k(const float* __restrict__ src,
                                                bf16* __restrict__ dst,
                                                int rows, int sk, int dk)
{
    size_t total = (size_t)rows * dk;
    for (size_t i = blockIdx.x * 256ull + threadIdx.x; i < total;
         i += (size_t)gridDim.x * 256) {
        int c = (int)(i % dk);
        int r = (int)(i / dk);
        dst[i] = __float2bfloat16(c < sk ? src[(size_t)r * sk + c] : 0.f);
    }
}

// ---------------- MFMA conv 3x3 SAME + bias + ReLU, NHWC --------------------
// Block: one y-row (128 px) x full COUT. LDS holds a 32-ci slab of the 3
// input rows: [3][130][40] shorts (pad 8 -> ~2-way banks). A-frags cached in
// VGPRs per (kc, ky); B via ds_read_b128.
template <int CIN, int COUT, int WM, int WN>
__global__ __launch_bounds__(256, 2) void conv_nhwc(
    const bf16* __restrict__ in,   // [img][y][x][CIN]
    const bf16* __restrict__ wT,   // [9][COUT][CIN]
    const float* __restrict__ bias,
    bf16* __restrict__ out)        // [img][y][x][COUT]
{
    constexpr int KC = CIN / 32;
    constexpr int MW = COUT / 16 / WM;
    constexpr int NW = 8 / WN;
    constexpr int CSL = 40;

    const int y = blockIdx.x;
    const int img = blockIdx.z;
    const int tid = threadIdx.x;
    const int wave = tid >> 6, lane = tid & 63;
    const int wm = wave % WM, wn = wave / WM;
    const int q = lane >> 4, n16 = lane & 15;

    __shared__ short smem[3 * 130 * CSL];

    f32x4 acc[MW][NW];
#pragma unroll
    for (int mt = 0; mt < MW; ++mt)
#pragma unroll
        for (int nt = 0; nt < NW; ++nt) acc[mt][nt] = f32x4{0.f, 0.f, 0.f, 0.f};

    const bf16* inImg = in + (size_t)img * HWPX * CIN;

    for (int kc = 0; kc < KC; ++kc) {
        if (kc) __syncthreads();
        // stage slab: 3 rows x 130 x x 4 granules of 8 ci
        for (int d = tid; d < 3 * 130 * 4; d += 256) {
            int g = d & 3;
            int x = (d >> 2) % 130;
            int r = (d >> 2) / 130;
            int yy = y + r - 1, xx = x - 1;
            bf16x8 v = (bf16x8)0;
            if ((unsigned)yy < 128u && (unsigned)xx < 128u)
                v = *(const bf16x8*)(const void*)(inImg +
                        ((size_t)yy * 128 + xx) * CIN + kc * 32 + g * 8);
            *(bf16x8*)(void*)&smem[(r * 130 + x) * CSL + g * 8] = v;
        }
        __syncthreads();

#pragma unroll
        for (int ky = 0; ky < 3; ++ky) {
            bf16x8 aF[3][MW];
#pragma unroll
            for (int kx = 0; kx < 3; ++kx)
#pragma unroll
                for (int mt = 0; mt < MW; ++mt) {
                    int co = (wm * MW + mt) * 16 + n16;
                    aF[kx][mt] = *(const bf16x8*)(const void*)(wT +
                        (((size_t)(ky * 3 + kx) * COUT + co) * CIN) + kc * 32 + q * 8);
                }
#pragma unroll
            for (int nt = 0; nt < NW; ++nt) {
#pragma unroll
                for (int kx = 0; kx < 3; ++kx) {
                    int xt = (wn * NW + nt) * 16 + n16 + kx;  // slot = out_x + kx
                    bf16x8 bF = *(const bf16x8*)(const void*)
                        &smem[(ky * 130 + xt) * CSL + q * 8];
#pragma unroll
                    for (int mt = 0; mt < MW; ++mt)
                        acc[mt][nt] = __builtin_amdgcn_mfma_f32_16x16x32_bf16(
                            aF[kx][mt], bF, acc[mt][nt], 0, 0, 0);
                }
            }
        }
    }

    // epilogue: C layout col=lane&15 (x), row=q*4+reg (co); NHWC 8B stores
#pragma unroll
    for (int mt = 0; mt < MW; ++mt) {
        int co0 = (wm * MW + mt) * 16 + q * 4;
#pragma unroll
        for (int nt = 0; nt < NW; ++nt) {
            int x = (wn * NW + nt) * 16 + n16;
            bf16 tmp[4];
#pragma unroll
            for (int r = 0; r < 4; ++r) {
                float v = acc[mt][nt][r] + bias[co0 + r];
                tmp[r] = __float2bfloat16(v > 0.f ? v : 0.f);
            }
            *reinterpret_cast<uint2*>(out + ((size_t)img * HWPX + y * 128 + x) * COUT + co0)
                = *reinterpret_cast<uint2*>(tmp);
        }
    }
}

// ---------------- L0 conv: NHWC8 input, kx folded into K --------------------
__global__ __launch_bounds__(256, 2) void conv0_nhwc(
    const bf16* __restrict__ in8,  // [img][y][x][8]
    const bf16* __restrict__ wT0,  // [3ky][32co][32k]
    const float* __restrict__ bias,
    bf16* __restrict__ out)        // [img][y][x][32]
{
    const int y = blockIdx.x;
    const int img = blockIdx.z;
    const int tid = threadIdx.x;
    const int wave = tid >> 6, lane = tid & 63;
    const int wm = wave & 1, wn = wave >> 1;   // WM=2, WN=2, MW=1, NW=4
    const int q = lane >> 4, n16 = lane & 15;

    __shared__ short smem[3 * 130 * 16];
    const bf16* inImg = in8 + (size_t)img * HWPX * 8;

    for (int d = tid; d < 3 * 130; d += 256) {
        int x = d % 130, r = d / 130;
        int yy = y + r - 1, xx = x - 1;
        bf16x8 v = (bf16x8)0;
        if ((unsigned)yy < 128u && (unsigned)xx < 128u)
            v = *(const bf16x8*)(const void*)(inImg + ((size_t)yy * 128 + xx) * 8);
        *(bf16x8*)(void*)&smem[(r * 130 + x) * 16] = v;
        *(bf16x8*)(void*)&smem[(r * 130 + x) * 16 + 8] = (bf16x8)0;
    }
    __syncthreads();

    f32x4 acc[4];
#pragma unroll
    for (int nt = 0; nt < 4; ++nt) acc[nt] = f32x4{0.f, 0.f, 0.f, 0.f};

    const int co = wm * 16 + n16;
#pragma unroll
    for (int ky = 0; ky < 3; ++ky) {
        bf16x8 aF = *(const bf16x8*)(const void*)(wT0 + ((size_t)(ky * 32 + co) * 32) + q * 8);
#pragma unroll
        for (int nt = 0; nt < 4; ++nt) {
            int x = (wn * 4 + nt) * 16 + n16;
            int off = (q < 3) ? (ky * 130 + x + q) * 16 : (ky * 130 + x) * 16 + 8;
            bf16x8 bF = *(const bf16x8*)(const void*)&smem[off];
            acc[nt] = __builtin_amdgcn_mfma_f32_16x16x32_bf16(aF, bF, acc[nt], 0, 0, 0);
        }
    }

    int co0 = wm * 16 + q * 4;
#pragma unroll
    for (int nt = 0; nt < 4; ++nt) {
        int x = (wn * 4 + nt) * 16 + n16;
        bf16 tmp[4];
#pragma unroll
        for (int r = 0; r < 4; ++r) {
            float v = acc[nt][r] + bias[co0 + r];
            tmp[r] = __float2bfloat16(v > 0.f ? v : 0.f);
        }
        *reinterpret_cast<uint2*>(out + ((size_t)img * HWPX + y * 128 + x) * 32 + co0)
            = *reinterpret_cast<uint2*>(tmp);
    }
}

// ---------------- spatial softmax, NHWC-16 input, block per image -----------
__global__ __launch_bounds__(1024) void softmax2_k(
    const bf16* __restrict__ act,  // [img][16384][16]
    float* __restrict__ feat, int imgBase)
{
    const int img = blockIdx.x;
    const int tid = threadIdx.x;
    const uint4* p = reinterpret_cast<const uint4*>(act + (size_t)img * HWPX * 16);
    __shared__ float red[3][16][16];
    __shared__ float bcast[16];

    float m[16];
#pragma unroll
    for (int c = 0; c < 16; ++c) m[c] = -1e30f;

    for (int px = tid; px < HWPX; px += 1024) {
        uint4 u0 = p[px * 2], u1 = p[px * 2 + 1];
        float v[16] = {bflo(u0.x), bfhi(u0.x), bflo(u0.y), bfhi(u0.y),
                       bflo(u0.z), bfhi(u0.z), bflo(u0.w), bfhi(u0.w),
                       bflo(u1.x), bfhi(u1.x), bflo(u1.y), bfhi(u1.y),
                       bflo(u1.z), bfhi(u1.z), bflo(u1.w), bfhi(u1.w)};
#pragma unroll
        for (int c = 0; c < 16; ++c) m[c] = fmaxf(m[c], v[c]);
    }
#pragma unroll
    for (int c = 0; c < 16; ++c)
        for (int s = 32; s; s >>= 1) m[c] = fmaxf(m[c], __shfl_xor(m[c], s));
    int wv = tid >> 6, ln = tid & 63;
    if (ln == 0)
#pragma unroll
        for (int c = 0; c < 16; ++c) red[0][wv][c] = m[c];
    __syncthreads();
    if (tid < 16) {
        float mm = -1e30f;
        for (int w = 0; w < 16; ++w) mm = fmaxf(mm, red[0][w][tid]);
        bcast[tid] = mm;
    }
    __syncthreads();
#pragma unroll
    for (int c = 0; c < 16; ++c) m[c] = bcast[c];
    __syncthreads();

    float s[16], sx[16], sy[16];
#pragma unroll
    for (int c = 0; c < 16; ++c) { s[c] = 0.f; sx[c] = 0.f; sy[c] = 0.f; }
    for (int px = tid; px < HWPX; px += 1024) {
        uint4 u0 = p[px * 2], u1 = p[px * 2 + 1];
        float v[16] = {bflo(u0.x), bfhi(u0.x), bflo(u0.y), bfhi(u0.y),
                       bflo(u0.z), bfhi(u0.z), bflo(u0.w), bfhi(u0.w),
                       bflo(u1.x), bfhi(u1.x), bflo(u1.y), bfhi(u1.y),
                       bflo(u1.z), bfhi(u1.z), bflo(u1.w), bfhi(u1.w)};
        float pxx = -1.f + (2.f / 127.f) * (px & 127);
        float pyy = -1.f + (2.f / 127.f) * (px >> 7);
#pragma unroll
        for (int c = 0; c < 16; ++c) {
            float e = expf(v[c] - m[c]);
            s[c] += e; sx[c] += e * pxx; sy[c] += e * pyy;
        }
    }
#pragma unroll
    for (int c = 0; c < 16; ++c)
        for (int st = 32; st; st >>= 1) {
            s[c] += __shfl_xor(s[c], st);
            sx[c] += __shfl_xor(sx[c], st);
            sy[c] += __shfl_xor(sy[c], st);
        }
    if (ln == 0)
#pragma unroll
        for (int c = 0; c < 16; ++c) {
            red[0][wv][c] = s[c]; red[1][wv][c] = sx[c]; red[2][wv][c] = sy[c];
        }
    __syncthreads();
    if (tid < 16) {
        float S = 0.f, SX = 0.f, SY = 0.f;
        for (int w = 0; w < 16; ++w) {
            S += red[0][w][tid]; SX += red[1][w][tid]; SY += red[2][w][tid];
        }
        feat[(size_t)(imgBase + img) * 32 + 2 * tid] = SX / S;
        feat[(size_t)(imgBase + img) * 32 + 2 * tid + 1] = SY / S;
    }
}

// ---------------- LSTM ------------------------------------------------------
__device__ inline float imgfeat(const float* featm, const float* feats,
                                int b, int t, int k)
{
    int idx = (b * 10 + t) * 32;
    return k < 32 ? featm[idx + k] : feats[idx + k - 32];
}

// bf16 weights, 4 threads per gate row, 128 blocks
__global__ __launch_bounds__(256) void lstm_gates2_k(
    const bf16* __restrict__ wih,   // [2048][K1] bf16 (K1 = 72 or 576)
    const bf16* __restrict__ whh,   // [2048][512] bf16
    const float* __restrict__ bih, const float* __restrict__ bhh,
    const float* __restrict__ states,
    const float* __restrict__ featm, const float* __restrict__ feats,
    const float* __restrict__ hprev, const float* __restrict__ hl,
    float* __restrict__ gates, int t, int K1)
{
    const int b = blockIdx.x >> 5;
    const int row0 = (blockIdx.x & 31) * 64;
    const int tid = threadIdx.x;
    __shared__ float xs[1088];

    for (int i = tid; i < K1; i += 256) {
        float v;
        if (hprev) {
            v = (i < 512) ? hprev[b * 512 + i] : imgfeat(featm, feats, b, t, i - 512);
        } else {
            v = (i < 6) ? states[(b * 10 + t) * 6 + i]
                        : (i < 70 ? imgfeat(featm, feats, b, t, i - 6) : 0.f);
        }
        xs[i] = v;
    }
    for (int i = tid; i < 512; i += 256) xs[K1 + i] = hl[b * 512 + i];
    __syncthreads();

    const int r = row0 + (tid >> 2);
    const int j = tid & 3;
    float acc = 0.f;

    const uint4* w1 = reinterpret_cast<const uint4*>(wih + (size_t)r * K1);
    const int G1 = K1 >> 3;
    for (int g = j; g < G1; g += 4) {
        uint4 u = w1[g];
        const float4* xv = reinterpret_cast<const float4*>(xs + g * 8);
        float4 x0 = xv[0], x1 = xv[1];
        acc += bflo(u.x) * x0.x + bfhi(u.x) * x0.y + bflo(u.y) * x0.z + bfhi(u.y) * x0.w
             + bflo(u.z) * x1.x + bfhi(u.z) * x1.y + bflo(u.w) * x1.z + bfhi(u.w) * x1.w;
    }
    const uint4* w2 = reinterpret_cast<const uint4*>(whh + (size_t)r * 512);
    const float* hsb = xs + K1;
    for (int g = j; g < 64; g += 4) {
        uint4 u = w2[g];
        const float4* xv = reinterpret_cast<const float4*>(hsb + g * 8);
        float4 x0 = xv[0], x1 = xv[1];
        acc += bflo(u.x) * x0.x + bfhi(u.x) * x0.y + bflo(u.y) * x0.z + bfhi(u.y) * x0.w
             + bflo(u.z) * x1.x + bfhi(u.z) * x1.y + bflo(u.w) * x1.z + bfhi(u.w) * x1.w;
    }
    acc += __shfl_xor(acc, 1);
    acc += __shfl_xor(acc, 2);
    if (j == 0) gates[b * 2048 + r] = acc + bih[r] + bhh[r];
}

// torch LSTMCell gate order i,f,g,o
__global__ __launch_bounds__(256) void lstm_combine_k(
    const float* __restrict__ gates, float* __restrict__ h, float* __restrict__ c)
{
    int gid = blockIdx.x * 256 + threadIdx.x;
    if (gid >= 2048) return;
    int b = gid >> 9, j = gid & 511;
    float gi = gates[b * 2048 + j];
    float gf = gates[b * 2048 + 512 + j];
    float gg = gates[b * 2048 + 1024 + j];
    float go = gates[b * 2048 + 1536 + j];
    float cp = c[b * 512 + j];
    float c2 = sigmoidf_(gf) * cp + sigmoidf_(gi) * tanhf(gg);
    float h2 = sigmoidf_(go) * tanhf(c2);
    c[b * 512 + j] = c2;
    h[b * 512 + j] = h2;
}

__global__ __launch_bounds__(64) void out_proj_k(
    const float* __restrict__ h5, const float* __restrict__ featm,
    const float* __restrict__ feats, const float* __restrict__ out_w,
    const float* __restrict__ out_b, float* __restrict__ out, int t)
{
    int tid = threadIdx.x;
    if (tid >= 24) return;
    int b = tid / 6, a = tid % 6;
    const float* wr = out_w + a * 576;
    float acc = out_b[a];
    for (int k = 0; k < 512; ++k) acc += wr[k] * h5[b * 512 + k];
    for (int k = 0; k < 64; ++k) acc += wr[512 + k] * imgfeat(featm, feats, b, t, k);
    out[(b * 10 + t) * 6 + a] = acc;
}

// ---------------- host orchestration ----------------------------------------
extern "C" void kernel_launch(void* const* d_in, const int* in_sizes, int n_in,
                              void* d_out, int out_size, void* d_ws, size_t ws_size,
                              hipStream_t stream)
{
    const float* seq_m = (const float*)d_in[0];
    const float* seq_s = (const float*)d_in[1];
    const float* states = (const float*)d_in[2];
    const float *cw[2][4], *cb[2][4];
    for (int cam = 0; cam < 2; ++cam)
        for (int j = 0; j < 4; ++j) {
            cw[cam][j] = (const float*)d_in[3 + cam * 8 + j * 2];
            cb[cam][j] = (const float*)d_in[3 + cam * 8 + j * 2 + 1];
        }
    const float* wih0  = (const float*)d_in[19];
    const float* whh0  = (const float*)d_in[20];
    const float* bih0  = (const float*)d_in[21];
    const float* bhh0  = (const float*)d_in[22];
    const float* wih_r = (const float*)d_in[23];
    const float* whh_r = (const float*)d_in[24];
    const float* bih_r = (const float*)d_in[25];
    const float* bhh_r = (const float*)d_in[26];
    const float* out_w = (const float*)d_in[27];
    const float* out_b = (const float*)d_in[28];
    float* out = (float*)d_out;

    // ---- workspace carve (256B-aligned) ----
    char* wsc = (char*)d_ws;
    auto carve = [&](size_t bytes) {
        char* p = wsc;
        wsc += (bytes + 255) & ~(size_t)255;
        return p;
    };
    float* featm = (float*)carve(40 * 32 * 4);
    float* feats = (float*)carve(40 * 32 * 4);
    float* hbuf  = (float*)carve(6 * 4 * 512 * 4);
    float* cbuf  = (float*)carve(6 * 4 * 512 * 4);
    float* gates = (float*)carve(4 * 2048 * 4);
    // conv weights
    const int wtElts[4] = {3 * 32 * 32, 9 * 64 * 32, 9 * 128 * 64, 9 * 16 * 128};
    bf16* wT[2][4];
    for (int cam = 0; cam < 2; ++cam)
        for (int j = 0; j < 4; ++j) wT[cam][j] = (bf16*)carve(wtElts[j] * 2);
    // LSTM bf16 weights
    bf16* wih0p = (bf16*)carve((size_t)2048 * 72 * 2);
    bf16* whh0b = (bf16*)carve((size_t)2048 * 512 * 2);
    bf16* wihrb = (bf16*)carve((size_t)5 * 2048 * 576 * 2);
    bf16* whhrb = (bf16*)carve((size_t)5 * 2048 * 512 * 2);

    size_t used = (size_t)(wsc - (char*)d_ws);
    size_t rem = ws_size > used ? ws_size - used : 0;
    int CH = 1;
    const int cands[8] = {40, 20, 10, 8, 5, 4, 2, 1};
    for (int i = 0; i < 8; ++i) {
        size_t need = (size_t)cands[i] * (8 + 128 + 64) * HWPX * 2;
        if (need <= rem) { CH = cands[i]; break; }
    }
    bf16* in8  = (bf16*)carve((size_t)CH * HWPX * 8 * 2);
    bf16* bufA = (bf16*)carve((size_t)CH * HWPX * 128 * 2);
    bf16* bufB = (bf16*)carve((size_t)CH * HWPX * 64 * 2);

    hipMemsetAsync(hbuf, 0, 2 * 6 * 4 * 512 * 4, stream);

    // ---- weight preps ----
    padcvt_k<<<256, 256, 0, stream>>>(wih0, wih0p, 2048, 70, 72);
    padcvt_k<<<1024, 256, 0, stream>>>(whh0, whh0b, 2048, 512, 512);
    padcvt_k<<<4096, 256, 0, stream>>>(wih_r, wihrb, 5 * 2048, 576, 576);
    padcvt_k<<<4096, 256, 0, stream>>>(whh_r, whhrb, 5 * 2048, 512, 512);
    for (int cam = 0; cam < 2; ++cam) {
        wprep0_k<<<12, 256, 0, stream>>>(cw[cam][0], wT[cam][0]);
        wprep_k<<<(wtElts[1] + 255) / 256, 256, 0, stream>>>(cw[cam][1], wT[cam][1], 32, 64);
        wprep_k<<<(wtElts[2] + 255) / 256, 256, 0, stream>>>(cw[cam][2], wT[cam][2], 64, 128);
        wprep_k<<<(wtElts[3] + 255) / 256, 256, 0, stream>>>(cw[cam][3], wT[cam][3], 128, 16);
    }

    // ---- CNN + spatial softmax ----
    for (int cam = 0; cam < 2; ++cam) {
        const float* src = cam ? seq_s : seq_m;
        float* feat = cam ? feats : featm;
        for (int c0 = 0; c0 < 40; c0 += CH) {
            int ch = (40 - c0) < CH ? (40 - c0) : CH;
            int npx = ch * HWPX;
            prep8_k<<<(npx + 255) / 256, 256, 0, stream>>>(
                src + (size_t)c0 * 3 * HWPX, in8, npx);
            conv0_nhwc<<<dim3(128, 1, ch), 256, 0, stream>>>(
                in8, wT[cam][0], cb[cam][0], bufA);
            conv_nhwc<32, 64, 2, 2><<<dim3(128, 1, ch), 256, 0, stream>>>(
                bufA, wT[cam][1], cb[cam][1], bufB);
            conv_nhwc<64, 128, 2, 2><<<dim3(128, 1, ch), 256, 0, stream>>>(
                bufB, wT[cam][2], cb[cam][2], bufA);
            conv_nhwc<128, 16, 1, 4><<<dim3(128, 1, ch), 256, 0, stream>>>(
                bufA, wT[cam][3], cb[cam][3], bufB);
            softmax2_k<<<ch, 1024, 0, stream>>>(bufB, feat, c0);
        }
    }

    // ---- LSTM over time ----
    for (int t = 0; t < 10; ++t) {
        lstm_gates2_k<<<128, 256, 0, stream>>>(wih0p, whh0b, bih0, bhh0, states,
                                               featm, feats, nullptr, hbuf, gates,
                                               t, 72);
        lstm_combine_k<<<8, 256, 0, stream>>>(gates, hbuf, cbuf);
        for (int l = 1; l < 6; ++l) {
            lstm_gates2_k<<<128, 256, 0, stream>>>(
                wihrb + (size_t)(l - 1) * 2048 * 576,
                whhrb + (size_t)(l - 1) * 2048 * 512,
                bih_r + (size_t)(l - 1) * 2048,
                bhh_r + (size_t)(l - 1) * 2048,
                states, featm, feats,
                hbuf + (size_t)(l - 1) * 2048, hbuf + (size_t)l * 2048,
                gates, t, 576);
            lstm_combine_k<<<8, 256, 0, stream>>>(gates, hbuf + (size_t)l * 2048,
                                                  cbuf + (size_t)l * 2048);
        }
        out_proj_k<<<1, 64, 0, stream>>>(hbuf + 5 * 2048, featm, feats,
                                         out_w, out_b, out, t);
    }
}

// Round 5
// 1936.325 us; speedup vs baseline: 5.3176x; 1.1637x over previous
//
#include <hip/hip_runtime.h>
#include <hip/hip_bf16.h>
#include <math.h>

typedef __hip_bfloat16 bf16;
typedef short bf16x8 __attribute__((ext_vector_type(8)));
typedef float f32x4 __attribute__((ext_vector_type(4)));

static constexpr int HWPX = 16384;  // 128*128

__device__ inline float sigmoidf_(float x) { return 1.0f / (1.0f + expf(-x)); }
__device__ inline float bflo(unsigned u) { return __uint_as_float(u << 16); }
__device__ inline float bfhi(unsigned u) { return __uint_as_float(u & 0xffff0000u); }

// async global->LDS, 16B per lane; lds ptr must be wave-uniform (lane i -> +i*16)
__device__ inline void gll16(const bf16* g, short* l) {
    __builtin_amdgcn_global_load_lds(
        (const __attribute__((address_space(1))) void*)g,
        (__attribute__((address_space(3))) void*)l, 16, 0, 0);
}

// ---------------- prep: LSTM weights -> bf16 (wih0 padded 70->72) -----------
__global__ __launch_bounds__(256) void prep_lstm_k(
    const float* __restrict__ wih0, const float* __restrict__ whh0,
    const float* __restrict__ wihr, const float* __restrict__ whhr,
    bf16* __restrict__ d0, bf16* __restrict__ d1,
    bf16* __restrict__ d2, bf16* __restrict__ d3)
{
    const size_t nA = 2048ull * 72, nB = 2048ull * 512;
    const size_t nC = 5ull * 2048 * 576, nD = 5ull * 2048 * 512;
    for (size_t i = blockIdx.x * 256ull + threadIdx.x; i < nA + nB + nC + nD;
         i += (size_t)gridDim.x * 256) {
        if (i < nA) {
            int c = (int)(i % 72), r = (int)(i / 72);
            d0[i] = __float2bfloat16(c < 70 ? wih0[(size_t)r * 70 + c] : 0.f);
        } else if (i < nA + nB) {
            size_t k = i - nA; d1[k] = __float2bfloat16(whh0[k]);
        } else if (i < nA + nB + nC) {
            size_t k = i - nA - nB; d2[k] = __float2bfloat16(wihr[k]);
        } else {
            size_t k = i - nA - nB - nC; d3[k] = __float2bfloat16(whhr[k]);
        }
    }
}

// ---------------- prep: conv weights, both cams, one dispatch ---------------
struct ConvW {
    const float* src[8];
    bf16* dst[8];
};

__global__ __launch_bounds__(256) void prep_conv_k(ConvW a)
{
    // per cam: L0 special 3072; L1 (32,64) 18432; L2 (64,128) 73728; L3 (128,16) 18432
    const int sizes[4] = {3072, 18432, 73728, 18432};
    const int cins[4] = {3, 32, 64, 128};
    const int couts[4] = {32, 64, 128, 16};
    int total = 2 * 113664;
    for (int idx = blockIdx.x * 256 + threadIdx.x; idx < total; idx += gridDim.x * 256) {
        int i = idx, cam = 0;
        if (i >= 113664) { cam = 1; i -= 113664; }
        int layer = 0;
        while (layer < 3 && i >= sizes[layer]) { i -= sizes[layer]; ++layer; }
        const float* w = a.src[cam * 4 + layer];
        bf16* d = a.dst[cam * 4 + layer];
        if (layer == 0) {
            // [3ky][32co][32k], k = kx*8 + c
            int k = i & 31, co = (i >> 5) & 31, ky = i >> 10;
            int kx = k >> 3, c = k & 7;
            float v = (kx < 3 && c < 3) ? w[((co * 3 + c) * 3 + ky) * 3 + kx] : 0.f;
            d[i] = __float2bfloat16(v);
        } else {
            // dst [tap][kc][q][co][8]
            int CIN = cins[layer], COUT = couts[layer], KC = CIN / 32;
            int e = i & 7;
            int t2 = i >> 3;
            int co = t2 % COUT;
            int t3 = t2 / COUT;
            int q = t3 & 3;
            int t4 = t3 >> 2;
            int kc = t4 % KC;
            int tap = t4 / KC;
            d[i] = __float2bfloat16(w[((size_t)(co * CIN + kc * 32 + q * 8 + e)) * 9 + tap]);
        }
    }
}

// slot helpers: row slab = 520 slots (130 x * 4 granules), swizzled
__device__ inline int swz(int x) { return (x ^ (x >> 2)) & 3; }

// ---------------- conv L0: fp32 NCHW in, NHWC-32 out ------------------------
__global__ __launch_bounds__(256, 4) void conv0_nhwc(
    const float* __restrict__ src,  // [img][3][128][128] fp32
    const bf16* __restrict__ wT0,   // [3ky][32co][32k]
    const float* __restrict__ bias,
    bf16* __restrict__ out)         // [img][y][x][32]
{
    const int y = blockIdx.x;
    const int img = blockIdx.z;
    const int tid = threadIdx.x;
    const int wave = tid >> 6, lane = tid & 63;
    const int wm = wave & 1, wn = wave >> 1;   // MW=1(16co), NW=4
    const int q = lane >> 4, n16 = lane & 15;

    __shared__ short smem[3 * 130 * 16];
    const float* inImg = src + (size_t)img * 3 * HWPX;

    for (int d = tid; d < 3 * 130; d += 256) {
        int x = d % 130, r = d / 130;
        int yy = y + r - 1, xx = x - 1;
        bf16 v8[8];
#pragma unroll
        for (int c = 0; c < 8; ++c) v8[c] = __float2bfloat16(0.f);
        if ((unsigned)yy < 128u && (unsigned)xx < 128u) {
            int o = yy * 128 + xx;
            v8[0] = __float2bfloat16(inImg[o]);
            v8[1] = __float2bfloat16(inImg[HWPX + o]);
            v8[2] = __float2bfloat16(inImg[2 * HWPX + o]);
        }
        *(bf16x8*)(void*)&smem[(r * 130 + x) * 16] = *(bf16x8*)(void*)v8;
        *(bf16x8*)(void*)&smem[(r * 130 + x) * 16 + 8] = (bf16x8)0;
    }
    __syncthreads();

    f32x4 acc[4];
#pragma unroll
    for (int nt = 0; nt < 4; ++nt) acc[nt] = f32x4{0.f, 0.f, 0.f, 0.f};

    const int co = wm * 16 + n16;
#pragma unroll
    for (int ky = 0; ky < 3; ++ky) {
        bf16x8 aF = *(const bf16x8*)(const void*)(wT0 + ((size_t)(ky * 32 + co) * 32) + q * 8);
#pragma unroll
        for (int nt = 0; nt < 4; ++nt) {
            int x = (wn * 4 + nt) * 16 + n16;
            int off = (q < 3) ? (ky * 130 + x + q) * 16 : (ky * 130 + x) * 16 + 8;
            bf16x8 bF = *(const bf16x8*)(const void*)&smem[off];
            acc[nt] = __builtin_amdgcn_mfma_f32_16x16x32_bf16(aF, bF, acc[nt], 0, 0, 0);
        }
    }

    int co0 = wm * 16 + q * 4;
#pragma unroll
    for (int nt = 0; nt < 4; ++nt) {
        int x = (wn * 4 + nt) * 16 + n16;
        bf16 tmp[4];
#pragma unroll
        for (int r = 0; r < 4; ++r) {
            float v = acc[nt][r] + bias[co0 + r];
            tmp[r] = __float2bfloat16(v > 0.f ? v : 0.f);
        }
        *reinterpret_cast<uint2*>(out + ((size_t)img * HWPX + y * 128 + x) * 32 + co0)
            = *reinterpret_cast<uint2*>(tmp);
    }
}

// ---------------- mid convs: NHWC, async gll staging, dbuf LDS --------------
template <int CIN, int COUT, int WM, int WN>
__global__ __launch_bounds__(256, 3) void conv_nhwc(
    const bf16* __restrict__ in,   // [img][y][x][CIN]
    const bf16* __restrict__ wT,   // [tap][kc][q][COUT][8]
    const float* __restrict__ bias,
    bf16* __restrict__ out,        // [img][y][x][COUT]
    const char* __restrict__ zpage)
{
    constexpr int KC = CIN / 32;
    constexpr int NB = (KC > 1) ? 2 : 1;
    constexpr int MW = COUT / 16 / WM;
    constexpr int NW = 8 / WN;

    const int y = blockIdx.x;
    const int img = blockIdx.z;
    const int tid = threadIdx.x;
    const int wave = tid >> 6, lane = tid & 63;
    const int wm = wave % WM, wn = wave / WM;
    const int q = lane >> 4, n16 = lane & 15;

    __shared__ short smem[NB][3 * 520 * 8];
    const bf16* inImg = in + (size_t)img * HWPX * CIN;

    // precompute per-thread staging source (kc-independent part)
    const bf16* sptr[7];
#pragma unroll
    for (int it = 0; it < 7; ++it) {
        int s = it * 256 + tid;
        int r = s / 520, s5 = s - r * 520;
        int x = s5 >> 2;
        int g = (s5 & 3) ^ swz(x);
        int yy = y + r - 1, xx = x - 1;
        bool ok = (s < 1560) && ((unsigned)yy < 128u) && ((unsigned)xx < 128u);
        sptr[it] = ok ? inImg + ((size_t)yy * 128 + xx) * CIN + g * 8
                      : (const bf16*)(zpage + (tid & 255) * 16);
    }
    auto stage = [&](int kc, int buf) {
#pragma unroll
        for (int it = 0; it < 7; ++it) {
            if (it * 256 + tid < 1560)
                gll16(sptr[it] + kc * 32, &smem[buf][it * 2048 + wave * 512]);
        }
    };

    f32x4 acc[MW][NW];
#pragma unroll
    for (int mt = 0; mt < MW; ++mt)
#pragma unroll
        for (int nt = 0; nt < NW; ++nt) acc[mt][nt] = f32x4{0.f, 0.f, 0.f, 0.f};

    stage(0, 0);
    for (int kc = 0; kc < KC; ++kc) {
        __syncthreads();                       // drains gll(kc) (issued a phase ago)
        if (kc + 1 < KC) stage(kc + 1, (kc + 1) % NB);
        const short* sb = smem[kc % NB];
#pragma unroll
        for (int ky = 0; ky < 3; ++ky) {
            bf16x8 aF[3][MW];
#pragma unroll
            for (int kx = 0; kx < 3; ++kx)
#pragma unroll
                for (int mt = 0; mt < MW; ++mt) {
                    int co = (wm * MW + mt) * 16 + n16;
                    aF[kx][mt] = *(const bf16x8*)(const void*)(wT +
                        ((((size_t)(ky * 3 + kx) * KC + kc) * 4 + q) * COUT + co) * 8);
                }
#pragma unroll
            for (int nt = 0; nt < NW; ++nt) {
#pragma unroll
                for (int kx = 0; kx < 3; ++kx) {
                    int x = (wn * NW + nt) * 16 + n16 + kx;
                    int slot = x * 4 + (q ^ swz(x));
                    bf16x8 bF = *(const bf16x8*)(const void*)&sb[ky * 4160 + slot * 8];
#pragma unroll
                    for (int mt = 0; mt < MW; ++mt)
                        acc[mt][nt] = __builtin_amdgcn_mfma_f32_16x16x32_bf16(
                            aF[kx][mt], bF, acc[mt][nt], 0, 0, 0);
                }
            }
        }
    }

#pragma unroll
    for (int mt = 0; mt < MW; ++mt) {
        int co0 = (wm * MW + mt) * 16 + q * 4;
#pragma unroll
        for (int nt = 0; nt < NW; ++nt) {
            int x = (wn * NW + nt) * 16 + n16;
            bf16 tmp[4];
#pragma unroll
            for (int r = 0; r < 4; ++r) {
                float v = acc[mt][nt][r] + bias[co0 + r];
                tmp[r] = __float2bfloat16(v > 0.f ? v : 0.f);
            }
            *reinterpret_cast<uint2*>(out + ((size_t)img * HWPX + y * 128 + x) * COUT + co0)
                = *reinterpret_cast<uint2*>(tmp);
        }
    }
}

// ---------------- conv L3 (128->16) fused with online-softmax partials ------
__global__ __launch_bounds__(256, 3) void conv4_ss(
    const bf16* __restrict__ in,   // [img][y][x][128]
    const bf16* __restrict__ wT,   // [tap][kc][q][16][8]
    const float* __restrict__ bias,
    float* __restrict__ partial,   // [img][16][128][4] {M,S,SX,-}
    const char* __restrict__ zpage)
{
    constexpr int CIN = 128, COUT = 16, KC = 4;
    const int y = blockIdx.x;
    const int img = blockIdx.z;
    const int tid = threadIdx.x;
    const int wave = tid >> 6, lane = tid & 63;
    const int q = lane >> 4, n16 = lane & 15;

    __shared__ short smem[2][3 * 520 * 8];
    __shared__ float sred[3][4][16];
    const bf16* inImg = in + (size_t)img * HWPX * CIN;

    const bf16* sptr[7];
#pragma unroll
    for (int it = 0; it < 7; ++it) {
        int s = it * 256 + tid;
        int r = s / 520, s5 = s - r * 520;
        int x = s5 >> 2;
        int g = (s5 & 3) ^ swz(x);
        int yy = y + r - 1, xx = x - 1;
        bool ok = (s < 1560) && ((unsigned)yy < 128u) && ((unsigned)xx < 128u);
        sptr[it] = ok ? inImg + ((size_t)yy * 128 + xx) * CIN + g * 8
                      : (const bf16*)(zpage + (tid & 255) * 16);
    }
    auto stage = [&](int kc, int buf) {
#pragma unroll
        for (int it = 0; it < 7; ++it) {
            if (it * 256 + tid < 1560)
                gll16(sptr[it] + kc * 32, &smem[buf][it * 2048 + wave * 512]);
        }
    };

    f32x4 acc[2];
    acc[0] = f32x4{0.f, 0.f, 0.f, 0.f};
    acc[1] = f32x4{0.f, 0.f, 0.f, 0.f};

    stage(0, 0);
    for (int kc = 0; kc < KC; ++kc) {
        __syncthreads();
        if (kc + 1 < KC) stage(kc + 1, (kc + 1) & 1);
        const short* sb = smem[kc & 1];
#pragma unroll
        for (int ky = 0; ky < 3; ++ky) {
            bf16x8 aF[3];
#pragma unroll
            for (int kx = 0; kx < 3; ++kx)
                aF[kx] = *(const bf16x8*)(const void*)(wT +
                    ((((size_t)(ky * 3 + kx) * KC + kc) * 4 + q) * COUT + n16) * 8);
#pragma unroll
            for (int nt = 0; nt < 2; ++nt) {
#pragma unroll
                for (int kx = 0; kx < 3; ++kx) {
                    int x = (wave * 2 + nt) * 16 + n16 + kx;
                    int slot = x * 4 + (q ^ swz(x));
                    bf16x8 bF = *(const bf16x8*)(const void*)&sb[ky * 4160 + slot * 8];
                    acc[nt] = __builtin_amdgcn_mfma_f32_16x16x32_bf16(aF[kx], bF, acc[nt], 0, 0, 0);
                }
            }
        }
    }

    // epilogue: bias+relu, per-(co) online-softmax partials for this y-row
    float v[2][4], px[2];
#pragma unroll
    for (int nt = 0; nt < 2; ++nt) {
        int x = (wave * 2 + nt) * 16 + n16;
        px[nt] = -1.f + (2.f / 127.f) * x;
#pragma unroll
        for (int r = 0; r < 4; ++r) {
            float t = acc[nt][r] + bias[q * 4 + r];
            v[nt][r] = t > 0.f ? t : 0.f;
        }
    }
    float ml[4];
#pragma unroll
    for (int r = 0; r < 4; ++r) {
        ml[r] = fmaxf(v[0][r], v[1][r]);
        ml[r] = fmaxf(ml[r], __shfl_xor(ml[r], 1));
        ml[r] = fmaxf(ml[r], __shfl_xor(ml[r], 2));
        ml[r] = fmaxf(ml[r], __shfl_xor(ml[r], 4));
        ml[r] = fmaxf(ml[r], __shfl_xor(ml[r], 8));
    }
    if (n16 == 0)
#pragma unroll
        for (int r = 0; r < 4; ++r) sred[0][wave][q * 4 + r] = ml[r];
    __syncthreads();
    float M[4];
#pragma unroll
    for (int r = 0; r < 4; ++r) {
        M[r] = sred[0][0][q * 4 + r];
        M[r] = fmaxf(M[r], sred[0][1][q * 4 + r]);
        M[r] = fmaxf(M[r], sred[0][2][q * 4 + r]);
        M[r] = fmaxf(M[r], sred[0][3][q * 4 + r]);
    }
    float s[4] = {0.f, 0.f, 0.f, 0.f}, sx[4] = {0.f, 0.f, 0.f, 0.f};
#pragma unroll
    for (int nt = 0; nt < 2; ++nt)
#pragma unroll
        for (int r = 0; r < 4; ++r) {
            float e = expf(v[nt][r] - M[r]);
            s[r] += e; sx[r] += e * px[nt];
        }
#pragma unroll
    for (int r = 0; r < 4; ++r) {
        s[r] += __shfl_xor(s[r], 1);  sx[r] += __shfl_xor(sx[r], 1);
        s[r] += __shfl_xor(s[r], 2);  sx[r] += __shfl_xor(sx[r], 2);
        s[r] += __shfl_xor(s[r], 4);  sx[r] += __shfl_xor(sx[r], 4);
        s[r] += __shfl_xor(s[r], 8);  sx[r] += __shfl_xor(sx[r], 8);
    }
    __syncthreads();
    if (n16 == 0)
#pragma unroll
        for (int r = 0; r < 4; ++r) {
            sred[1][wave][q * 4 + r] = s[r];
            sred[2][wave][q * 4 + r] = sx[r];
        }
    __syncthreads();
    if (tid < 16) {
        float S = sred[1][0][tid] + sred[1][1][tid] + sred[1][2][tid] + sred[1][3][tid];
        float SX = sred[2][0][tid] + sred[2][1][tid] + sred[2][2][tid] + sred[2][3][tid];
        float Mv = fmaxf(fmaxf(sred[0][0][tid], sred[0][1][tid]),
                         fmaxf(sred[0][2][tid], sred[0][3][tid]));
        float* pp = partial + (((size_t)img * 16 + tid) * 128 + y) * 4;
        pp[0] = Mv; pp[1] = S; pp[2] = SX;
    }
}

// ---------------- merge row partials -> (ex, ey) ----------------------------
__global__ __launch_bounds__(256) void ssmerge_k(
    const float* __restrict__ partial, float* __restrict__ feat, int imgBase)
{
    const int img = blockIdx.x;
    const int tid = threadIdx.x;
    const int co = tid >> 4, s = tid & 15;
    const float* base = partial + ((size_t)img * 16 + co) * 128 * 4;
    float M = -1e30f, S = 0.f, SX = 0.f, SY = 0.f;
    for (int y = s; y < 128; y += 16) {
        float m = base[y * 4], sv = base[y * 4 + 1], sxv = base[y * 4 + 2];
        float py = -1.f + (2.f / 127.f) * y;
        float Mn = fmaxf(M, m);
        float w0 = expf(M - Mn), w1 = expf(m - Mn);
        S = S * w0 + sv * w1;
        SX = SX * w0 + sxv * w1;
        SY = SY * w0 + sv * py * w1;
        M = Mn;
    }
#pragma unroll
    for (int mask = 1; mask < 16; mask <<= 1) {
        float Mo = __shfl_xor(M, mask), So = __shfl_xor(S, mask);
        float SXo = __shfl_xor(SX, mask), SYo = __shfl_xor(SY, mask);
        float Mn = fmaxf(M, Mo);
        float w0 = expf(M - Mn), w1 = expf(Mo - Mn);
        S = S * w0 + So * w1; SX = SX * w0 + SXo * w1; SY = SY * w0 + SYo * w1;
        M = Mn;
    }
    if (s == 0) {
        feat[(size_t)(imgBase + img) * 32 + 2 * co] = SX / S;
        feat[(size_t)(imgBase + img) * 32 + 2 * co + 1] = SY / S;
    }
}

// ---------------- LSTM: one dispatch per cell -------------------------------
__device__ inline float imgfeat(const float* featm, const float* feats,
                                int b, int t, int k)
{
    int idx = (b * 10 + t) * 32;
    return k < 32 ? featm[idx + k] : feats[idx + k - 32];
}

__global__ __launch_bounds__(256) void lstm_cell_k(
    const bf16* __restrict__ wih, const bf16* __restrict__ whh,
    const float* __restrict__ bih, const float* __restrict__ bhh,
    const float* __restrict__ states,
    const float* __restrict__ featm, const float* __restrict__ feats,
    const float* __restrict__ hprev,   // layer l-1 h at t (null for l=0)
    const float* __restrict__ hold,    // layer l h at t-1
    float* __restrict__ hnew,          // layer l h at t (out)
    float* __restrict__ cst,           // layer l c (in/out)
    int t, int K1)
{
    const int XS = K1 + 512;
    __shared__ float xs[4 * 1088];
    const int tid = threadIdx.x;
    for (int i = tid; i < 4 * XS; i += 256) {
        int b = i / XS, k = i - b * XS;
        float v;
        if (k < K1) {
            if (hprev) v = (k < 512) ? hprev[b * 512 + k]
                                     : imgfeat(featm, feats, b, t, k - 512);
            else       v = (k < 6) ? states[(b * 10 + t) * 6 + k]
                                   : (k < 70 ? imgfeat(featm, feats, b, t, k - 6) : 0.f);
        } else {
            v = hold[b * 512 + (k - K1)];
        }
        xs[b * XS + k] = v;
    }
    __syncthreads();

    const int b = tid >> 6;
    const int jloc = (tid >> 4) & 3;
    const int sub = tid & 15;
    const int j = blockIdx.x * 4 + jloc;
    const float* xb = xs + b * XS;
    const float* hp = xb + K1;
    float d[4] = {0.f, 0.f, 0.f, 0.f};
    const int nb1 = K1 >> 3;
#pragma unroll
    for (int r = 0; r < 4; ++r) {
        const uint4* w1 = reinterpret_cast<const uint4*>(wih + (size_t)(j + r * 512) * K1);
        for (int g = sub; g < nb1; g += 16) {
            uint4 u = w1[g]; const float* xp = xb + g * 8;
            d[r] += bflo(u.x) * xp[0] + bfhi(u.x) * xp[1] + bflo(u.y) * xp[2] + bfhi(u.y) * xp[3]
                  + bflo(u.z) * xp[4] + bfhi(u.z) * xp[5] + bflo(u.w) * xp[6] + bfhi(u.w) * xp[7];
        }
        const uint4* w2 = reinterpret_cast<const uint4*>(whh + (size_t)(j + r * 512) * 512);
        for (int g = sub; g < 64; g += 16) {
            uint4 u = w2[g]; const float* xp = hp + g * 8;
            d[r] += bflo(u.x) * xp[0] + bfhi(u.x) * xp[1] + bflo(u.y) * xp[2] + bfhi(u.y) * xp[3]
                  + bflo(u.z) * xp[4] + bfhi(u.z) * xp[5] + bflo(u.w) * xp[6] + bfhi(u.w) * xp[7];
        }
    }
#pragma unroll
    for (int r = 0; r < 4; ++r) {
        d[r] += __shfl_xor(d[r], 1);
        d[r] += __shfl_xor(d[r], 2);
        d[r] += __shfl_xor(d[r], 4);
        d[r] += __shfl_xor(d[r], 8);
    }
    if (sub == 0) {
        float gi = d[0] + bih[j] + bhh[j];
        float gf = d[1] + bih[j + 512] + bhh[j + 512];
        float gg = d[2] + bih[j + 1024] + bhh[j + 1024];
        float go = d[3] + bih[j + 1536] + bhh[j + 1536];
        float cp = cst[b * 512 + j];
        float c2 = sigmoidf_(gf) * cp + sigmoidf_(gi) * tanhf(gg);
        float h2 = sigmoidf_(go) * tanhf(c2);
        cst[b * 512 + j] = c2;
        hnew[b * 512 + j] = h2;
    }
}

__global__ __launch_bounds__(64) void out_proj_k(
    const float* __restrict__ h5, const float* __restrict__ featm,
    const float* __restrict__ feats, const float* __restrict__ out_w,
    const float* __restrict__ out_b, float* __restrict__ out, int t)
{
    int tid = threadIdx.x;
    if (tid >= 24) return;
    int b = tid / 6, a = tid % 6;
    const float* wr = out_w + a * 576;
    float acc = out_b[a];
    for (int k = 0; k < 512; ++k) acc += wr[k] * h5[b * 512 + k];
    for (int k = 0; k < 64; ++k) acc += wr[512 + k] * imgfeat(featm, feats, b, t, k);
    out[(b * 10 + t) * 6 + a] = acc;
}

// ---------------- host orchestration ----------------------------------------
extern "C" void kernel_launch(void* const* d_in, const int* in_sizes, int n_in,
                              void* d_out, int out_size, void* d_ws, size_t ws_size,
                              hipStream_t stream)
{
    const float* seq_m = (const float*)d_in[0];
    const float* seq_s = (const float*)d_in[1];
    const float* states = (const float*)d_in[2];
    const float *cw[2][4], *cb[2][4];
    for (int cam = 0; cam < 2; ++cam)
        for (int j = 0; j < 4; ++j) {
            cw[cam][j] = (const float*)d_in[3 + cam * 8 + j * 2];
            cb[cam][j] = (const float*)d_in[3 + cam * 8 + j * 2 + 1];
        }
    const float* wih0  = (const float*)d_in[19];
    const float* whh0  = (const float*)d_in[20];
    const float* bih0  = (const float*)d_in[21];
    const float* bhh0  = (const float*)d_in[22];
    const float* wih_r = (const float*)d_in[23];
    const float* whh_r = (const float*)d_in[24];
    const float* bih_r = (const float*)d_in[25];
    const float* bhh_r = (const float*)d_in[26];
    const float* out_w = (const float*)d_in[27];
    const float* out_b = (const float*)d_in[28];
    float* out = (float*)d_out;

    // ---- workspace carve (256B-aligned) ----
    char* wsc = (char*)d_ws;
    auto carve = [&](size_t bytes) {
        char* p = wsc;
        wsc += (bytes + 255) & ~(size_t)255;
        return p;
    };
    float* featm = (float*)carve(40 * 32 * 4);
    float* feats = (float*)carve(40 * 32 * 4);
    float* hbuf  = (float*)carve(2 * 6 * 4 * 512 * 4);  // two t-parities
    float* cbuf  = (float*)carve(6 * 4 * 512 * 4);
    char*  zpage = carve(8192);
    float* partial = (float*)carve((size_t)40 * 16 * 128 * 4 * 4);
    // conv weights [tap][kc][q][co][8]
    const int wtElts[4] = {3072, 18432, 73728, 18432};
    bf16* wT[2][4];
    for (int cam = 0; cam < 2; ++cam)
        for (int j = 0; j < 4; ++j) wT[cam][j] = (bf16*)carve(wtElts[j] * 2);
    // LSTM bf16 weights
    bf16* wih0p = (bf16*)carve((size_t)2048 * 72 * 2);
    bf16* whh0b = (bf16*)carve((size_t)2048 * 512 * 2);
    bf16* wihrb = (bf16*)carve((size_t)5 * 2048 * 576 * 2);
    bf16* whhrb = (bf16*)carve((size_t)5 * 2048 * 512 * 2);

    size_t used = (size_t)(wsc - (char*)d_ws);
    size_t rem = ws_size > used ? ws_size - used : 0;
    int CH = 1;
    const int cands[8] = {40, 20, 10, 8, 5, 4, 2, 1};
    for (int i = 0; i < 8; ++i) {
        size_t need = (size_t)cands[i] * (128 + 64) * HWPX * 2;
        if (need <= rem) { CH = cands[i]; break; }
    }
    bf16* bufA = (bf16*)carve((size_t)CH * HWPX * 128 * 2);  // 32ch or 128ch
    bf16* bufB = (bf16*)carve((size_t)CH * HWPX * 64 * 2);

    // zero h parities, c, zero-page (contiguous carves)
    hipMemsetAsync(hbuf, 0, (2 * 6 * 4 * 512 + 6 * 4 * 512) * 4 + 8192, stream);

    // ---- weight preps (2 dispatches) ----
    prep_lstm_k<<<8192, 256, 0, stream>>>(wih0, whh0, wih_r, whh_r,
                                          wih0p, whh0b, wihrb, whhrb);
    ConvW cwArg;
    for (int cam = 0; cam < 2; ++cam)
        for (int j = 0; j < 4; ++j) {
            cwArg.src[cam * 4 + j] = cw[cam][j];
            cwArg.dst[cam * 4 + j] = wT[cam][j];
        }
    prep_conv_k<<<888, 256, 0, stream>>>(cwArg);

    // ---- CNN + fused spatial softmax ----
    for (int cam = 0; cam < 2; ++cam) {
        const float* src = cam ? seq_s : seq_m;
        for (int c0 = 0; c0 < 40; c0 += CH) {
            int ch = (40 - c0) < CH ? (40 - c0) : CH;
            conv0_nhwc<<<dim3(128, 1, ch), 256, 0, stream>>>(
                src + (size_t)c0 * 3 * HWPX, wT[cam][0], cb[cam][0], bufA);
            conv_nhwc<32, 64, 2, 2><<<dim3(128, 1, ch), 256, 0, stream>>>(
                bufA, wT[cam][1], cb[cam][1], bufB, zpage);
            conv_nhwc<64, 128, 2, 2><<<dim3(128, 1, ch), 256, 0, stream>>>(
                bufB, wT[cam][2], cb[cam][2], bufA, zpage);
            conv4_ss<<<dim3(128, 1, ch), 256, 0, stream>>>(
                bufA, wT[cam][3], cb[cam][3],
                partial + (size_t)c0 * 16 * 128 * 4, zpage);
        }
        ssmerge_k<<<40, 256, 0, stream>>>(partial, cam ? feats : featm, 0);
    }

    // ---- LSTM over time (1 dispatch per cell) ----
    float* hA = hbuf;                  // parity 0 (t even reads)
    float* hB = hbuf + 6 * 4 * 512;    // parity 1
    for (int t = 0; t < 10; ++t) {
        float* hin  = (t & 1) ? hB : hA;
        float* hout = (t & 1) ? hA : hB;
        lstm_cell_k<<<128, 256, 0, stream>>>(
            wih0p, whh0b, bih0, bhh0, states, featm, feats,
            nullptr, hin, hout, cbuf, t, 72);
        for (int l = 1; l < 6; ++l) {
            lstm_cell_k<<<128, 256, 0, stream>>>(
                wihrb + (size_t)(l - 1) * 2048 * 576,
                whhrb + (size_t)(l - 1) * 2048 * 512,
                bih_r + (size_t)(l - 1) * 2048,
                bhh_r + (size_t)(l - 1) * 2048,
                states, featm, feats,
                hout + (size_t)(l - 1) * 2048,
                hin + (size_t)l * 2048,
                hout + (size_t)l * 2048,
                cbuf + (size_t)l * 2048, t, 576);
        }
        out_proj_k<<<1, 64, 0, stream>>>(hout + 5 * 2048, featm, feats,
                                         out_w, out_b, out, t);
    }
}